// Round 5
// baseline (368.072 us; speedup 1.0000x reference)
//
#include <hip/hip_runtime.h>
#include <hip/hip_bf16.h>

#define N_GRAPHS 200
#define NPG      500
#define N_NODES_ 100000
#define N_EDGES_ 1600000
#define DIN      64
#define DG       128
#define SEQ      20
#define HL       128
#define G4       512
#define BWIN     (N_GRAPHS - SEQ + 1)  // 181
#define NPART    64
#define EPB      (N_EDGES_/NPART)      // 25000
#define NCNT     (N_GRAPHS*NPART)      // 12800
#define GPARTS   4                     // blocks per graph in k_gcn
#define TNPB     125                   // nodes per k_gcn block
#define TNODES   128                   // padded LDS tile

__device__ __forceinline__ float sigmoidf_(float v){ return 1.0f/(1.0f+expf(-v)); }

// K1: per-(block,graph) edge counts via LDS histogram (no global atomics)
__global__ __launch_bounds__(256) void k_count(const int* __restrict__ src,
                                               int* __restrict__ cnt) {
  __shared__ int bins[N_GRAPHS];
  int b = blockIdx.x, t = threadIdx.x;
  for (int i = t; i < N_GRAPHS; i += 256) bins[i] = 0;
  __syncthreads();
  int e0 = b*EPB;
  for (int i = t; i < EPB; i += 256) atomicAdd(&bins[src[e0+i]/NPG], 1);
  __syncthreads();
  for (int g = t; g < N_GRAPHS; g += 256) cnt[g*NPART + b] = bins[g];
}

// K2: exclusive scan of 12800 counts in one block
__global__ __launch_bounds__(1024) void k_pscan(int* __restrict__ cnt) {
  __shared__ int sA[1024], sB[1024];
  int t = threadIdx.x;
  int base = t*13;
  int loc[13]; int s = 0;
  #pragma unroll
  for (int j = 0; j < 13; ++j) {
    int idx = base + j;
    int v = (idx < NCNT) ? cnt[idx] : 0;
    loc[j] = s; s += v;
  }
  sA[t] = s; __syncthreads();
  int* cur = sA; int* nxt = sB;
  for (int off = 1; off < 1024; off <<= 1) {
    nxt[t] = cur[t] + ((t >= off) ? cur[t-off] : 0);
    __syncthreads();
    int* tmp = cur; cur = nxt; nxt = tmp;
  }
  int excl = cur[t] - s;
  #pragma unroll
  for (int j = 0; j < 13; ++j) {
    int idx = base + j;
    if (idx < NCNT) cnt[idx] = excl + loc[j];
  }
}

// K3: deterministic partition by graph; packed (src_local<<9 | dst_local)
__global__ __launch_bounds__(256) void k_part(const int* __restrict__ src,
                                              const int* __restrict__ dst,
                                              const int* __restrict__ cnt,
                                              int* __restrict__ part) {
  __shared__ int cur[N_GRAPHS];
  int b = blockIdx.x, t = threadIdx.x;
  for (int g = t; g < N_GRAPHS; g += 256) cur[g] = cnt[g*NPART + b];
  __syncthreads();
  int e0 = b*EPB;
  for (int i = t; i < EPB; i += 256) {
    int s = src[e0+i], d = dst[e0+i];
    int g = s / NPG;
    int sl = s - g*NPG, dl = d - g*NPG;
    int pos = atomicAdd(&cur[g], 1);
    part[pos] = (sl << 9) | dl;
  }
}

// K4: per-graph counting sort -> global sorted src list + node metadata
__global__ __launch_bounds__(512) void k_sort(const int* __restrict__ cnt,
    const int* __restrict__ part, unsigned short* __restrict__ sorted_all,
    float* __restrict__ so_all, int* __restrict__ e_end, int* __restrict__ e_deg) {
  __shared__ int indeg[NPG], outdeg[NPG], off[NPG];
  __shared__ int sA[512], sB[512];
  int g = blockIdx.x, t = threadIdx.x;
  int seg0 = cnt[g*NPART];
  int seg1 = (g == N_GRAPHS-1) ? N_EDGES_ : cnt[(g+1)*NPART];
  if (t < NPG) { indeg[t] = 0; outdeg[t] = 0; }
  __syncthreads();
  for (int e = seg0 + t; e < seg1; e += 512) {
    int p = part[e];
    atomicAdd(&indeg[p & 511], 1);
    atomicAdd(&outdeg[p >> 9], 1);
  }
  __syncthreads();
  int v = (t < NPG) ? indeg[t] : 0;
  sA[t] = v; __syncthreads();
  int* cur = sA; int* nxt = sB;
  for (int o = 1; o < 512; o <<= 1) {
    nxt[t] = cur[t] + ((t >= o) ? cur[t-o] : 0);
    __syncthreads();
    int* tmp = cur; cur = nxt; nxt = tmp;
  }
  if (t < NPG) off[t] = cur[t] - v;
  __syncthreads();
  for (int e = seg0 + t; e < seg1; e += 512) {
    int p = part[e];
    int pos = atomicAdd(&off[p & 511], 1);
    sorted_all[seg0 + pos] = (unsigned short)(p >> 9);
  }
  __syncthreads();
  if (t < NPG) {
    so_all[g*NPG + t] = rsqrtf((float)max(outdeg[t], 1));
    e_end[g*NPG + t]  = seg0 + off[t];
    e_deg[g*NPG + t]  = indeg[t];
  }
}

// K5: aggregation — one wave per node, quarter-wave x 4-unroll per edge
__global__ __launch_bounds__(256) void k_agg(const float* __restrict__ x,
    const float* __restrict__ so_all, const int* __restrict__ e_end,
    const int* __restrict__ e_deg, const unsigned short* __restrict__ sorted_all,
    float* __restrict__ hpre) {
  int t = threadIdx.x;
  int n = (blockIdx.x << 2) + (t >> 6);
  if (n >= N_NODES_) return;
  int lane = t & 63, q = lane >> 4, ql = lane & 15;
  int end = e_end[n], deg = e_deg[n], start = end - deg;
  int g = n / NPG;
  const float4* xg = ((const float4*)x) + (size_t)g*NPG*16;
  const float* sog = so_all + g*NPG;
  float4 acc = make_float4(0.f, 0.f, 0.f, 0.f);
  for (int i = start + (q << 2); i < end; i += 16) {
    int sj[4];
    #pragma unroll
    for (int j = 0; j < 4; ++j) sj[j] = (i + j < end) ? (int)sorted_all[i+j] : -1;
    #pragma unroll
    for (int j = 0; j < 4; ++j) if (sj[j] >= 0) {
      float sc = sog[sj[j]];
      float4 xv = xg[(size_t)sj[j]*16 + ql];
      acc.x += xv.x*sc; acc.y += xv.y*sc; acc.z += xv.z*sc; acc.w += xv.w*sc;
    }
  }
  acc.x += __shfl_xor(acc.x, 16); acc.y += __shfl_xor(acc.y, 16);
  acc.z += __shfl_xor(acc.z, 16); acc.w += __shfl_xor(acc.w, 16);
  acc.x += __shfl_xor(acc.x, 32); acc.y += __shfl_xor(acc.y, 32);
  acc.z += __shfl_xor(acc.z, 32); acc.w += __shfl_xor(acc.w, 32);
  if (q == 0) {
    float sn = rsqrtf((float)max(deg, 1));
    float4 r = make_float4(acc.x*sn, acc.y*sn, acc.z*sn, acc.w*sn);
    ((float4*)hpre)[(size_t)n*16 + ql] = r;
  }
}

// K6: LDS-tiled GEMM + ReLU + partial pool. Thread = 4 dims x 4 nodes register tile.
__global__ __launch_bounds__(256) void k_gcn(const float* __restrict__ hpre,
    const float* __restrict__ w_gcn, const float* __restrict__ b_gcn,
    float* __restrict__ hgpart) {
  __shared__ float hT[TNODES*DIN];   // 32 KB  hT[n][k]
  __shared__ float wT[DIN*DG];       // 32 KB  wT[k][d]
  __shared__ float pS[8*DG];         // 4 KB
  int t = threadIdx.x, bb = blockIdx.x;
  int g = bb >> 2, p = bb & 3;
  int nbase = g*NPG + p*TNPB;
  for (int i = t; i < DIN*DG/4; i += 256)
    ((float4*)wT)[i] = ((const float4*)w_gcn)[i];
  for (int i = t; i < TNODES*16; i += 256) {
    int n = i >> 4;
    ((float4*)hT)[i] = (n < TNPB) ? ((const float4*)hpre)[(size_t)(nbase+n)*16 + (i & 15)]
                                  : make_float4(0.f,0.f,0.f,0.f);
  }
  __syncthreads();
  int dg = t & 31, ng = t >> 5;      // dim group (4 dims), node group
  int d0 = dg*4;
  float4 bias = ((const float4*)b_gcn)[dg];
  float psum[4] = {0.f,0.f,0.f,0.f};
  for (int c = 0; c < 4; ++c) {
    int nb = c*32 + ng*4;
    float acc[4][4];
    #pragma unroll
    for (int j = 0; j < 4; ++j) {
      acc[j][0]=bias.x; acc[j][1]=bias.y; acc[j][2]=bias.z; acc[j][3]=bias.w;
    }
    #pragma unroll
    for (int k4 = 0; k4 < 16; ++k4) {
      int k = k4*4;
      float4 w0 = *(const float4*)&wT[(k+0)*DG + d0];
      float4 w1 = *(const float4*)&wT[(k+1)*DG + d0];
      float4 w2 = *(const float4*)&wT[(k+2)*DG + d0];
      float4 w3 = *(const float4*)&wT[(k+3)*DG + d0];
      #pragma unroll
      for (int j = 0; j < 4; ++j) {
        float4 h4 = *(const float4*)&hT[(nb+j)*DIN + k];
        acc[j][0] = fmaf(h4.x,w0.x, fmaf(h4.y,w1.x, fmaf(h4.z,w2.x, fmaf(h4.w,w3.x, acc[j][0]))));
        acc[j][1] = fmaf(h4.x,w0.y, fmaf(h4.y,w1.y, fmaf(h4.z,w2.y, fmaf(h4.w,w3.y, acc[j][1]))));
        acc[j][2] = fmaf(h4.x,w0.z, fmaf(h4.y,w1.z, fmaf(h4.z,w2.z, fmaf(h4.w,w3.z, acc[j][2]))));
        acc[j][3] = fmaf(h4.x,w0.w, fmaf(h4.y,w1.w, fmaf(h4.z,w2.w, fmaf(h4.w,w3.w, acc[j][3]))));
      }
    }
    #pragma unroll
    for (int j = 0; j < 4; ++j) {
      if (nb + j < TNPB) {
        psum[0] += fmaxf(acc[j][0], 0.f);
        psum[1] += fmaxf(acc[j][1], 0.f);
        psum[2] += fmaxf(acc[j][2], 0.f);
        psum[3] += fmaxf(acc[j][3], 0.f);
      }
    }
  }
  #pragma unroll
  for (int i = 0; i < 4; ++i) pS[ng*DG + d0 + i] = psum[i];
  __syncthreads();
  if (t < DG) {
    float s = 0.f;
    #pragma unroll
    for (int ngg = 0; ngg < 8; ++ngg) s += pS[ngg*DG + t];
    hgpart[(size_t)bb*DG + t] = s;
  }
}

// K7: combine partials, divide by node count
__global__ void k_pool(const float* __restrict__ hgpart, float* __restrict__ hg) {
  int idx = blockIdx.x*blockDim.x + threadIdx.x;
  if (idx >= N_GRAPHS*DG) return;
  int g = idx >> 7, d = idx & 127;
  float s = 0.0f;
  #pragma unroll
  for (int p = 0; p < GPARTS; ++p) s += hgpart[(size_t)(g*GPARTS+p)*DG + d];
  hg[idx] = s * (1.0f/NPG);
}

// K8: per-graph input projection
__global__ __launch_bounds__(512) void k_proj(const float* __restrict__ hg,
    const float* __restrict__ w_ih, const float* __restrict__ b_ih,
    float* __restrict__ proj) {
  __shared__ __align__(16) float hS[HL];
  int g = blockIdx.x, r = threadIdx.x;
  if (r < HL) hS[r] = hg[g*HL + r];
  __syncthreads();
  const float4* wr = (const float4*)(w_ih + (size_t)r*HL);
  const float4* hv = (const float4*)hS;
  float acc = b_ih[r];
  #pragma unroll
  for (int k4 = 0; k4 < 32; ++k4) {
    float4 w4 = wr[k4]; float4 h4 = hv[k4];
    acc += w4.x*h4.x + w4.y*h4.y + w4.z*h4.z + w4.w*h4.w;
  }
  proj[(size_t)g*G4 + r] = acc;
}

// K9: LSTM, block per window, thread per gate-row, w_hh row in VGPRs
__global__ __launch_bounds__(512) void k_lstm(const float* __restrict__ proj,
    const float* __restrict__ w_hh, const float* __restrict__ b_hh,
    const float* __restrict__ w_fc, const float* __restrict__ b_fc,
    float* __restrict__ out) {
  __shared__ __align__(16) float hS[HL];
  __shared__ float gS[G4];
  int b = blockIdx.x, r = threadIdx.x;
  float wreg[HL];
  const float4* wr = (const float4*)(w_hh + (size_t)r*HL);
  #pragma unroll
  for (int k4 = 0; k4 < 32; ++k4) {
    float4 w4 = wr[k4];
    wreg[k4*4+0]=w4.x; wreg[k4*4+1]=w4.y; wreg[k4*4+2]=w4.z; wreg[k4*4+3]=w4.w;
  }
  float bh = b_hh[r];
  float c = 0.0f;
  if (r < HL) hS[r] = 0.0f;
  __syncthreads();
  for (int l = 0; l < SEQ; ++l) {
    float acc = proj[(size_t)(b+l)*G4 + r] + bh;
    const float4* hv = (const float4*)hS;
    #pragma unroll
    for (int k4 = 0; k4 < 32; ++k4) {
      float4 h4 = hv[k4];
      acc += h4.x*wreg[k4*4] + h4.y*wreg[k4*4+1] + h4.z*wreg[k4*4+2] + h4.w*wreg[k4*4+3];
    }
    gS[r] = acc;
    __syncthreads();
    if (r < HL) {
      float gi = sigmoidf_(gS[r]);
      float gf = sigmoidf_(gS[HL + r]);
      float gg = tanhf(gS[2*HL + r]);
      float go = sigmoidf_(gS[3*HL + r]);
      c = gf*c + gi*gg;
      hS[r] = go * tanhf(c);
    }
    __syncthreads();
  }
  if (r < 64) {
    float s = hS[r]*w_fc[r] + hS[r+64]*w_fc[r+64];
    #pragma unroll
    for (int off = 32; off > 0; off >>= 1) s += __shfl_down(s, off);
    if (r == 0) out[b] = s + b_fc[0];
  }
}

extern "C" void kernel_launch(void* const* d_in, const int* in_sizes, int n_in,
                              void* d_out, int out_size, void* d_ws, size_t ws_size,
                              hipStream_t stream) {
  const float* x     = (const float*)d_in[0];
  const int*   src   = (const int*)d_in[1];
  const int*   dst   = (const int*)d_in[2];
  const float* w_gcn = (const float*)d_in[4];
  const float* b_gcn = (const float*)d_in[5];
  const float* w_ih  = (const float*)d_in[6];
  const float* w_hh  = (const float*)d_in[7];
  const float* b_ih  = (const float*)d_in[8];
  const float* b_hh  = (const float*)d_in[9];
  const float* w_fc  = (const float*)d_in[10];
  const float* b_fc  = (const float*)d_in[11];
  float* out = (float*)d_out;

  char* ws = (char*)d_ws;
  size_t off = 0;
  auto alloc = [&](size_t bytes) -> void* {
    void* p = ws + off; off += (bytes + 255) & ~(size_t)255; return p;
  };
  int* cnt     = (int*)alloc((size_t)NCNT*4);
  int* part    = (int*)alloc((size_t)N_EDGES_*4);
  unsigned short* sorted_all = (unsigned short*)alloc((size_t)N_EDGES_*2);
  float* so_all = (float*)alloc((size_t)N_NODES_*4);
  int* e_end   = (int*)alloc((size_t)N_NODES_*4);
  int* e_deg   = (int*)alloc((size_t)N_NODES_*4);
  float* hpre  = (float*)alloc((size_t)N_NODES_*DIN*4);
  float* hgpart= (float*)alloc((size_t)N_GRAPHS*GPARTS*DG*4);
  float* hg    = (float*)alloc((size_t)N_GRAPHS*DG*4);
  float* proj  = (float*)alloc((size_t)N_GRAPHS*G4*4);
  (void)ws_size; (void)in_sizes; (void)n_in; (void)out_size;

  k_count<<<NPART, 256, 0, stream>>>(src, cnt);
  k_pscan<<<1, 1024, 0, stream>>>(cnt);
  k_part<<<NPART, 256, 0, stream>>>(src, dst, cnt, part);
  k_sort<<<N_GRAPHS, 512, 0, stream>>>(cnt, part, sorted_all, so_all, e_end, e_deg);
  k_agg<<<(N_NODES_+3)/4, 256, 0, stream>>>(x, so_all, e_end, e_deg, sorted_all, hpre);
  k_gcn<<<N_GRAPHS*GPARTS, 256, 0, stream>>>(hpre, w_gcn, b_gcn, hgpart);
  k_pool<<<(N_GRAPHS*DG+255)/256, 256, 0, stream>>>(hgpart, hg);
  k_proj<<<N_GRAPHS, 512, 0, stream>>>(hg, w_ih, b_ih, proj);
  k_lstm<<<BWIN, 512, 0, stream>>>(proj, w_hh, b_hh, w_fc, b_fc, out);
}